// Round 2
// baseline (337.535 us; speedup 1.0000x reference)
//
#include <hip/hip_runtime.h>
#include <hip/hip_bf16.h>
#include <math.h>

#define B_   4
#define T_   2048
#define KDIM 1024
#define H_   16
#define D_   64
#define BH_  (B_*H_)      // 64
#define M_   (B_*T_)      // 8192

typedef __bf16 bf16;
typedef __bf16 bf16x8 __attribute__((ext_vector_type(8)));
typedef __bf16 bf16x4 __attribute__((ext_vector_type(4)));
typedef float  f32x4  __attribute__((ext_vector_type(4)));
typedef float  f32x16 __attribute__((ext_vector_type(16)));
typedef unsigned int u32;
typedef u32 u32x4 __attribute__((ext_vector_type(4)));

static __device__ __forceinline__ f32x4 mfma16(bf16x8 a, bf16x8 b, f32x4 c) {
    return __builtin_amdgcn_mfma_f32_16x16x32_bf16(a, b, c, 0, 0, 0);
}
static __device__ __forceinline__ f32x16 mfma32(bf16x8 a, bf16x8 b, f32x16 c) {
    return __builtin_amdgcn_mfma_f32_32x32x16_bf16(a, b, c, 0, 0, 0);
}
static __device__ __forceinline__ float exp2_fast(float x) {
#if __has_builtin(__builtin_amdgcn_exp2f)
    return __builtin_amdgcn_exp2f(x);
#else
    float r; asm("v_exp_f32 %0, %1" : "=v"(r) : "v"(x)); return r;
#endif
}

// ---------------- fp32 -> bf16 conversion (vectorized) ----------------
__global__ void cvt_f32_to_bf16(const float* __restrict__ src, bf16* __restrict__ dst, int n4) {
    int i = blockIdx.x * blockDim.x + threadIdx.x;
    if (i >= n4) return;
    float4 v = reinterpret_cast<const float4*>(src)[i];
    bf16x4 o;
    o.x = (bf16)v.x; o.y = (bf16)v.y; o.z = (bf16)v.z; o.w = (bf16)v.w;
    reinterpret_cast<bf16x4*>(dst)[i] = o;
}

// ---------------- QKV projection GEMM ----------------
__global__ __launch_bounds__(256) void proj_gemm(
    const bf16* __restrict__ xb, const bf16* __restrict__ Wall,
    bf16* __restrict__ Qb, bf16* __restrict__ Kb, bf16* __restrict__ Vtb)
{
    __shared__ __align__(16) bf16 Asm[128*64];
    __shared__ __align__(16) bf16 Bsm[128*64];

    const int tid  = threadIdx.x;
    const int wid  = tid >> 6;
    const int lane = tid & 63;
    const int l15  = lane & 15, l4 = lane >> 4;
    const int wr = wid >> 1, wc = wid & 1;
    const int row0 = blockIdx.x * 128;
    const int col0 = blockIdx.y * 128;
    const int wz   = blockIdx.z;
    const bf16* Wp = Wall + (size_t)wz * KDIM * KDIM;

    f32x4 acc[4][4] = {};

    for (int kt = 0; kt < KDIM/64; ++kt) {
        const int k0 = kt * 64;
        __syncthreads();
#pragma unroll
        for (int i = 0; i < 4; ++i) {
            int chunk = i*256 + tid;
            int rr = chunk >> 3;
            int cc = (chunk & 7) * 8;
            const bf16* ga = xb + (size_t)(row0 + rr)*KDIM + k0 + cc;
            bf16* la = Asm + (size_t)(i*256 + wid*64)*8;
            __builtin_amdgcn_global_load_lds(
                (const __attribute__((address_space(1))) void*)ga,
                (__attribute__((address_space(3))) void*)la, 16, 0, 0);
        }
#pragma unroll
        for (int i = 0; i < 4; ++i) {
            int chunk = i*256 + tid;
            int rr = chunk >> 3;
            int cc = (chunk & 7) * 8;
            const bf16* gb = Wp + (size_t)(col0 + rr)*KDIM + k0 + cc;
            bf16* lb = Bsm + (size_t)(i*256 + wid*64)*8;
            __builtin_amdgcn_global_load_lds(
                (const __attribute__((address_space(1))) void*)gb,
                (__attribute__((address_space(3))) void*)lb, 16, 0, 0);
        }
        asm volatile("s_waitcnt vmcnt(0)" ::: "memory");
        __syncthreads();

#pragma unroll
        for (int kk = 0; kk < 2; ++kk) {
            bf16x8 af[4], bfr[4];
#pragma unroll
            for (int m = 0; m < 4; ++m)
                af[m] = *reinterpret_cast<const bf16x8*>(Asm + (wr*64 + m*16 + l15)*64 + kk*32 + l4*8);
#pragma unroll
            for (int n = 0; n < 4; ++n)
                bfr[n] = *reinterpret_cast<const bf16x8*>(Bsm + (wc*64 + n*16 + l15)*64 + kk*32 + l4*8);
#pragma unroll
            for (int m = 0; m < 4; ++m)
#pragma unroll
                for (int n = 0; n < 4; ++n)
                    acc[m][n] = mfma16(af[m], bfr[n], acc[m][n]);
        }
    }

    const float osc = (wz == 0) ? 0.18033688011112042f : 1.0f;  // 0.125*log2(e) folded into Q
#pragma unroll
    for (int m = 0; m < 4; ++m)
#pragma unroll
        for (int n = 0; n < 4; ++n)
#pragma unroll
            for (int r = 0; r < 4; ++r) {
                int gi = row0 + wr*64 + m*16 + l4*4 + r;
                int gj = col0 + wc*64 + n*16 + l15;
                bf16 o = (bf16)(acc[m][n][r] * osc);
                int bb = gi >> 11, tt = gi & (T_-1);
                int hh = gj >> 6,  dd = gj & (D_-1);
                size_t bh = (size_t)bb*H_ + hh;
                if (wz == 0)      Qb [(bh*T_ + tt)*D_ + dd] = o;
                else if (wz == 1) Kb [(bh*T_ + tt)*D_ + dd] = o;
                else              Vtb[(bh*D_ + dd)*T_ + tt] = o;
            }
}

// ---------------- causal flash attention, swapped-QK^T 32x32, no LDS/barriers ----------------
__global__ __launch_bounds__(256) void flash_attn2(
    const bf16* __restrict__ Qb, const bf16* __restrict__ Kb,
    const bf16* __restrict__ Vtb, float* __restrict__ out)
{
    const int tid  = threadIdx.x;
    const int wid  = tid >> 6;
    const int lane = tid & 63;
    const int l31  = lane & 31;
    const int hi   = lane >> 5;

    const int W  = blockIdx.x * 4 + wid;
    const int bh = W >> 6;
    const int qi = 63 - (W & 63);            // heavy q-tiles first
    const int q0 = qi * 32;
    const int q_abs = q0 + l31;

    const bf16* qp = Qb + ((size_t)bh*T_ + q_abs)*D_ + hi*8;
    const bf16x8 qf0 = *reinterpret_cast<const bf16x8*>(qp);
    const bf16x8 qf1 = *reinterpret_cast<const bf16x8*>(qp + 16);
    const bf16x8 qf2 = *reinterpret_cast<const bf16x8*>(qp + 32);
    const bf16x8 qf3 = *reinterpret_cast<const bf16x8*>(qp + 48);

    f32x16 o0 = {}; f32x16 o1 = {};
    float lsum = 0.f;
    bf16x8 pB_stash;   // second 16-kv chunk fragment, written by subtile()

    const bf16* kbase = Kb  + (size_t)bh*T_*D_;
    const bf16* vb0   = Vtb + (size_t)bh*D_*T_ + (size_t)l31*T_;
    const bf16* vb1   = vb0 + (size_t)32*T_;

    const int ntmax = (q0 + 31) >> 6;
    const int tmask = q_abs - 4*hi;

    auto subtile = [&](int kvb, bool maskit) -> bf16x8 {
        const bf16* kp = kbase + ((size_t)(kvb + l31))*D_ + hi*8;
        bf16x8 k0 = *reinterpret_cast<const bf16x8*>(kp);
        bf16x8 k1 = *reinterpret_cast<const bf16x8*>(kp + 16);
        bf16x8 k2 = *reinterpret_cast<const bf16x8*>(kp + 32);
        bf16x8 k3 = *reinterpret_cast<const bf16x8*>(kp + 48);
        f32x16 s = {};
        s = mfma32(k0, qf0, s);
        s = mfma32(k1, qf1, s);
        s = mfma32(k2, qf2, s);
        s = mfma32(k3, qf3, s);
        const int tlim = tmask - kvb;
        float p[16];
#pragma unroll
        for (int r = 0; r < 16; ++r) {
            const int crow0 = (r & 3) + 8*(r >> 2);
            float sv = s[r];
            if (maskit) sv = (crow0 > tlim) ? -INFINITY : sv;
            p[r] = exp2_fast(sv);
        }
        {
            float a0 = p[0]+p[1],   a1 = p[2]+p[3],   a2 = p[4]+p[5],   a3 = p[6]+p[7];
            float a4 = p[8]+p[9],   a5 = p[10]+p[11], a6 = p[12]+p[13], a7 = p[14]+p[15];
            float b0 = a0+a1, b1 = a2+a3, b2 = a4+a5, b3 = a6+a7;
            lsum += (b0+b1) + (b2+b3);
        }
        u32 w[8];
#pragma unroll
        for (int i = 0; i < 8; ++i) {
            u32 wv;
            asm("v_cvt_pk_bf16_f32 %0, %1, %2" : "=v"(wv) : "v"(p[2*i]), "v"(p[2*i+1]));
            w[i] = wv;
        }
        u32 a0w = w[0], a2w = w[2];
        asm("v_permlane32_swap_b32 %0, %1" : "+v"(a0w), "+v"(a2w));
        u32 a1w = w[1], a3w = w[3];
        asm("v_permlane32_swap_b32 %0, %1" : "+v"(a1w), "+v"(a3w));
        u32 b0w = w[4], b2w = w[6];
        asm("v_permlane32_swap_b32 %0, %1" : "+v"(b0w), "+v"(b2w));
        u32 b1w = w[5], b3w = w[7];
        asm("v_permlane32_swap_b32 %0, %1" : "+v"(b1w), "+v"(b3w));
        u32x4 A0 = {a0w, a1w, a2w, a3w};
        u32x4 A1 = {b0w, b1w, b2w, b3w};
        pB_stash = __builtin_bit_cast(bf16x8, A1);
        return __builtin_bit_cast(bf16x8, A0);
    };

    for (int nt = 0; nt <= ntmax; ++nt) {
        const bool partial = (nt == ntmax);
        const int  nkt = (!partial || (q0 & 32)) ? 2 : 1;
        const int  ct0 = nt * 64;

        bf16x8 pc0 = subtile(ct0, partial);
        bf16x8 pc1 = pB_stash;
        {
            bf16x8 va = *reinterpret_cast<const bf16x8*>(vb0 + ct0 + hi*8);
            bf16x8 vb = *reinterpret_cast<const bf16x8*>(vb1 + ct0 + hi*8);
            o0 = mfma32(va, pc0, o0);
            o1 = mfma32(vb, pc0, o1);
            va = *reinterpret_cast<const bf16x8*>(vb0 + ct0 + 16 + hi*8);
            vb = *reinterpret_cast<const bf16x8*>(vb1 + ct0 + 16 + hi*8);
            o0 = mfma32(va, pc1, o0);
            o1 = mfma32(vb, pc1, o1);
        }
        if (nkt == 2) {
            bf16x8 pc2 = subtile(ct0 + 32, partial);
            bf16x8 pc3 = pB_stash;
            bf16x8 va = *reinterpret_cast<const bf16x8*>(vb0 + ct0 + 32 + hi*8);
            bf16x8 vb = *reinterpret_cast<const bf16x8*>(vb1 + ct0 + 32 + hi*8);
            o0 = mfma32(va, pc2, o0);
            o1 = mfma32(vb, pc2, o1);
            va = *reinterpret_cast<const bf16x8*>(vb0 + ct0 + 48 + hi*8);
            vb = *reinterpret_cast<const bf16x8*>(vb1 + ct0 + 48 + hi*8);
            o0 = mfma32(va, pc3, o0);
            o1 = mfma32(vb, pc3, o1);
        }
    }

    lsum += __shfl_xor(lsum, 32);
    const float inv = 1.0f / lsum;
    const int bb = bh >> 4, hh = bh & 15;
    float* orow = out + ((size_t)bb*T_ + q_abs)*KDIM + hh*64 + hi*4;
#pragma unroll
    for (int g = 0; g < 4; ++g) {
        f32x4 v0, v1;
#pragma unroll
        for (int j = 0; j < 4; ++j) { v0[j] = o0[g*4+j]*inv; v1[j] = o1[g*4+j]*inv; }
        *reinterpret_cast<f32x4*>(orow + g*8)      = v0;
        *reinterpret_cast<f32x4*>(orow + 32 + g*8) = v1;
    }
}

extern "C" void kernel_launch(void* const* d_in, const int* in_sizes, int n_in,
                              void* d_out, int out_size, void* d_ws, size_t ws_size,
                              hipStream_t stream) {
    (void)in_sizes; (void)n_in; (void)out_size; (void)ws_size;
    const float* x  = (const float*)d_in[0];
    const float* Wq = (const float*)d_in[1];
    const float* Wk = (const float*)d_in[2];
    const float* Wv = (const float*)d_in[3];
    float* out = (float*)d_out;

    bf16* xb  = (bf16*)d_ws;
    bf16* Wb  = xb + (size_t)M_*KDIM;
    bf16* Qb  = Wb + (size_t)3*KDIM*KDIM;
    bf16* Kb  = Qb + (size_t)M_*KDIM;
    bf16* Vtb = Kb + (size_t)M_*KDIM;

    const int n4x = M_*KDIM/4;
    const int n4w = KDIM*KDIM/4;
    cvt_f32_to_bf16<<<(n4x+255)/256, 256, 0, stream>>>(x,  xb, n4x);
    cvt_f32_to_bf16<<<(n4w+255)/256, 256, 0, stream>>>(Wq, Wb,               n4w);
    cvt_f32_to_bf16<<<(n4w+255)/256, 256, 0, stream>>>(Wk, Wb + (size_t)KDIM*KDIM,   n4w);
    cvt_f32_to_bf16<<<(n4w+255)/256, 256, 0, stream>>>(Wv, Wb + (size_t)2*KDIM*KDIM, n4w);

    proj_gemm<<<dim3(M_/128, KDIM/128, 3), 256, 0, stream>>>(xb, Wb, Qb, Kb, Vtb);
    flash_attn2<<<dim3(BH_*16), 256, 0, stream>>>(Qb, Kb, Vtb, out);
}

// Round 3
// 181.086 us; speedup vs baseline: 1.8640x; 1.8640x over previous
//
#include <hip/hip_runtime.h>
#include <hip/hip_bf16.h>
#include <math.h>

#define B_   4
#define T_   2048
#define KDIM 1024
#define H_   16
#define D_   64
#define BH_  (B_*H_)      // 64
#define M_   (B_*T_)      // 8192

typedef __bf16 bf16;
typedef __bf16 bf16x8 __attribute__((ext_vector_type(8)));
typedef __bf16 bf16x4 __attribute__((ext_vector_type(4)));
typedef float  f32x4  __attribute__((ext_vector_type(4)));
typedef float  f32x16 __attribute__((ext_vector_type(16)));
typedef unsigned int u32;
typedef u32 u32x4 __attribute__((ext_vector_type(4)));

static __device__ __forceinline__ f32x4 mfma16(bf16x8 a, bf16x8 b, f32x4 c) {
    return __builtin_amdgcn_mfma_f32_16x16x32_bf16(a, b, c, 0, 0, 0);
}
static __device__ __forceinline__ f32x16 mfma32(bf16x8 a, bf16x8 b, f32x16 c) {
    return __builtin_amdgcn_mfma_f32_32x32x16_bf16(a, b, c, 0, 0, 0);
}
static __device__ __forceinline__ float exp2_fast(float x) {
    float r; asm("v_exp_f32 %0, %1" : "=v"(r) : "v"(x)); return r;
}

// ---------------- fp32 -> bf16 conversion (vectorized) ----------------
__global__ void cvt_f32_to_bf16(const float* __restrict__ src, bf16* __restrict__ dst, int n4) {
    int i = blockIdx.x * blockDim.x + threadIdx.x;
    if (i >= n4) return;
    float4 v = reinterpret_cast<const float4*>(src)[i];
    bf16x4 o;
    o.x = (bf16)v.x; o.y = (bf16)v.y; o.z = (bf16)v.z; o.w = (bf16)v.w;
    reinterpret_cast<bf16x4*>(dst)[i] = o;
}

// ---------------- QKV projection GEMM (unchanged, proven) ----------------
__global__ __launch_bounds__(256) void proj_gemm(
    const bf16* __restrict__ xb, const bf16* __restrict__ Wall,
    bf16* __restrict__ Qb, bf16* __restrict__ Kb, bf16* __restrict__ Vtb)
{
    __shared__ __align__(16) bf16 Asm[128*64];
    __shared__ __align__(16) bf16 Bsm[128*64];

    const int tid  = threadIdx.x;
    const int wid  = tid >> 6;
    const int lane = tid & 63;
    const int l15  = lane & 15, l4 = lane >> 4;
    const int wr = wid >> 1, wc = wid & 1;
    const int row0 = blockIdx.x * 128;
    const int col0 = blockIdx.y * 128;
    const int wz   = blockIdx.z;
    const bf16* Wp = Wall + (size_t)wz * KDIM * KDIM;

    f32x4 acc[4][4] = {};

    for (int kt = 0; kt < KDIM/64; ++kt) {
        const int k0 = kt * 64;
        __syncthreads();
#pragma unroll
        for (int i = 0; i < 4; ++i) {
            int chunk = i*256 + tid;
            int rr = chunk >> 3;
            int cc = (chunk & 7) * 8;
            const bf16* ga = xb + (size_t)(row0 + rr)*KDIM + k0 + cc;
            bf16* la = Asm + (size_t)(i*256 + wid*64)*8;
            __builtin_amdgcn_global_load_lds(
                (const __attribute__((address_space(1))) void*)ga,
                (__attribute__((address_space(3))) void*)la, 16, 0, 0);
        }
#pragma unroll
        for (int i = 0; i < 4; ++i) {
            int chunk = i*256 + tid;
            int rr = chunk >> 3;
            int cc = (chunk & 7) * 8;
            const bf16* gb = Wp + (size_t)(col0 + rr)*KDIM + k0 + cc;
            bf16* lb = Bsm + (size_t)(i*256 + wid*64)*8;
            __builtin_amdgcn_global_load_lds(
                (const __attribute__((address_space(1))) void*)gb,
                (__attribute__((address_space(3))) void*)lb, 16, 0, 0);
        }
        asm volatile("s_waitcnt vmcnt(0)" ::: "memory");
        __syncthreads();

#pragma unroll
        for (int kk = 0; kk < 2; ++kk) {
            bf16x8 af[4], bfr[4];
#pragma unroll
            for (int m = 0; m < 4; ++m)
                af[m] = *reinterpret_cast<const bf16x8*>(Asm + (wr*64 + m*16 + l15)*64 + kk*32 + l4*8);
#pragma unroll
            for (int n = 0; n < 4; ++n)
                bfr[n] = *reinterpret_cast<const bf16x8*>(Bsm + (wc*64 + n*16 + l15)*64 + kk*32 + l4*8);
#pragma unroll
            for (int m = 0; m < 4; ++m)
#pragma unroll
                for (int n = 0; n < 4; ++n)
                    acc[m][n] = mfma16(af[m], bfr[n], acc[m][n]);
        }
    }

    const float osc = (wz == 0) ? 0.18033688011112042f : 1.0f;  // 0.125*log2(e) folded into Q
#pragma unroll
    for (int m = 0; m < 4; ++m)
#pragma unroll
        for (int n = 0; n < 4; ++n)
#pragma unroll
            for (int r = 0; r < 4; ++r) {
                int gi = row0 + wr*64 + m*16 + l4*4 + r;
                int gj = col0 + wc*64 + n*16 + l15;
                bf16 o = (bf16)(acc[m][n][r] * osc);
                int bb = gi >> 11, tt = gi & (T_-1);
                int hh = gj >> 6,  dd = gj & (D_-1);
                size_t bh = (size_t)bb*H_ + hh;
                if (wz == 0)      Qb [(bh*T_ + tt)*D_ + dd] = o;
                else if (wz == 1) Kb [(bh*T_ + tt)*D_ + dd] = o;
                else              Vtb[(bh*D_ + dd)*T_ + tt] = o;
            }
}

// ---------------- causal flash attention v3 ----------------
// 4 waves/block, 128 q-rows/block, K/V staged in swizzled LDS (shared by waves),
// reg-prefetch of next tile, in-register softmax via swapped QK^T (32x32 MFMA).
__global__ __launch_bounds__(256) void flash_attn3(
    const bf16* __restrict__ Qb, const bf16* __restrict__ Kb,
    const bf16* __restrict__ Vtb, float* __restrict__ out)
{
    __shared__ __align__(16) char Ksm[8192];   // [kv=64][d=64] bf16, rows XOR-swizzled
    __shared__ __align__(16) char Vsm[8192];   // [d=64][kv=64] bf16, rows XOR-swizzled

    const int tid  = threadIdx.x;
    const int wid  = tid >> 6;
    const int lane = tid & 63;
    const int l31  = lane & 31;
    const int hi   = lane >> 5;

    // bijective XCD swizzle: each XCD gets 8 contiguous bh (K/V L2-resident)
    const int orig = blockIdx.x;                       // 1024 blocks, 1024%8==0
    const int wg   = (orig & 7) * 128 + (orig >> 3);
    const int bh   = wg >> 4;
    const int qblk = (15 - (wg & 15)) * 128;           // heavy tiles first per bh
    const int q0   = qblk + wid * 32;
    const int q_abs = q0 + l31;

    // Q fragments (B-operand): lane holds Q[q=l31][d = j*16 + hi*8 + 0..7], prescaled
    const bf16* qp = Qb + ((size_t)bh*T_ + q_abs)*D_ + hi*8;
    bf16x8 qf[4];
#pragma unroll
    for (int j = 0; j < 4; ++j)
        qf[j] = *reinterpret_cast<const bf16x8*>(qp + j*16);

    const bf16* kbase = Kb  + (size_t)bh*T_*D_;
    const bf16* vbase = Vtb + (size_t)bh*D_*T_;

    f32x16 o0 = {}; f32x16 o1 = {};
    float lsum = 0.f;

    const int my_nt  = (q0 + 31) >> 6;      // this wave's last kv tile
    const int blk_nt = qblk/64 + 1;         // block's last kv tile
    const int tmaskb = q_abs - 4*hi;

    // staging geometry: thread stages chunks {tid, tid+256} (16B each) of K and V tiles
    const int r0 = tid >> 3,          r1 = (tid + 256) >> 3;
    const int e0 = (tid & 7) * 8,     e1 = e0;          // (c&7) identical for c and c+256
    const u32 lds0 = (u32)((r0*128 + e0*2) ^ ((r0 & 7) << 4));
    const u32 lds1 = (u32)((r1*128 + e1*2) ^ ((r1 & 7) << 4));

    u32x4 kr0, kr1, vr0, vr1;
    auto issue = [&](int nt) {
        kr0 = *reinterpret_cast<const u32x4*>(kbase + ((size_t)(nt*64 + r0))*D_ + e0);
        kr1 = *reinterpret_cast<const u32x4*>(kbase + ((size_t)(nt*64 + r1))*D_ + e1);
        vr0 = *reinterpret_cast<const u32x4*>(vbase + (size_t)r0*T_ + nt*64 + e0);
        vr1 = *reinterpret_cast<const u32x4*>(vbase + (size_t)r1*T_ + nt*64 + e1);
    };
    issue(0);

    // one 32-kv subtile from LDS: QK^T -> exp -> pack two PV B-fragments
    auto subtile = [&](int s, int kvb_abs, bool maskit, bf16x8& pA, bf16x8& pB) {
        f32x16 sacc = {};
        const int row = s*32 + l31;
        const int sw  = (row & 7) << 4;
#pragma unroll
        for (int j = 0; j < 4; ++j) {
            bf16x8 kf = *reinterpret_cast<const bf16x8*>(Ksm + ((row*128 + j*32 + hi*16) ^ sw));
            sacc = mfma32(kf, qf[j], sacc);
        }
        const int tlim = tmaskb - kvb_abs;
        float p[16];
#pragma unroll
        for (int r = 0; r < 16; ++r) {
            const int crow0 = (r & 3) + 8*(r >> 2);
            float sv = sacc[r];
            if (maskit) sv = (crow0 > tlim) ? -INFINITY : sv;
            p[r] = exp2_fast(sv);
        }
        {
            float a0 = p[0]+p[1],   a1 = p[2]+p[3],   a2 = p[4]+p[5],   a3 = p[6]+p[7];
            float a4 = p[8]+p[9],   a5 = p[10]+p[11], a6 = p[12]+p[13], a7 = p[14]+p[15];
            lsum += ((a0+a1) + (a2+a3)) + ((a4+a5) + (a6+a7));
        }
        u32 w[8];
#pragma unroll
        for (int i = 0; i < 8; ++i) {
            u32 wv;
            asm("v_cvt_pk_bf16_f32 %0, %1, %2" : "=v"(wv) : "v"(p[2*i]), "v"(p[2*i+1]));
            w[i] = wv;
        }
        u32 a0w = w[0], a2w = w[2];
        asm("v_permlane32_swap_b32 %0, %1" : "+v"(a0w), "+v"(a2w));
        u32 a1w = w[1], a3w = w[3];
        asm("v_permlane32_swap_b32 %0, %1" : "+v"(a1w), "+v"(a3w));
        u32 b0w = w[4], b2w = w[6];
        asm("v_permlane32_swap_b32 %0, %1" : "+v"(b0w), "+v"(b2w));
        u32 b1w = w[5], b3w = w[7];
        asm("v_permlane32_swap_b32 %0, %1" : "+v"(b1w), "+v"(b3w));
        u32x4 A0 = {a0w, a1w, a2w, a3w};
        u32x4 A1 = {b0w, b1w, b2w, b3w};
        pA = __builtin_bit_cast(bf16x8, A0);
        pB = __builtin_bit_cast(bf16x8, A1);
    };

    // PV for one 16-kv slice: A = V^T fragments (two d-tiles), B = P fragment
    auto pv = [&](int ks, bf16x8 pf) {
        const int swv = (l31 & 7) << 4;
        const int colb = ks*32 + hi*16;
        bf16x8 v0 = *reinterpret_cast<const bf16x8*>(Vsm + ((l31*128 + colb) ^ swv));
        bf16x8 v1 = *reinterpret_cast<const bf16x8*>(Vsm + (((32 + l31)*128 + colb) ^ swv));
        o0 = mfma32(v0, pf, o0);
        o1 = mfma32(v1, pf, o1);
    };

    for (int nt = 0; nt <= blk_nt; ++nt) {
        __syncthreads();                       // everyone done reading previous tile
        *reinterpret_cast<u32x4*>(Ksm + lds0) = kr0;
        *reinterpret_cast<u32x4*>(Ksm + lds1) = kr1;
        *reinterpret_cast<u32x4*>(Vsm + lds0) = vr0;
        *reinterpret_cast<u32x4*>(Vsm + lds1) = vr1;
        __syncthreads();                       // tile visible
        if (nt < blk_nt) issue(nt + 1);        // prefetch hides under compute

        if (nt <= my_nt) {
            const bool partial = (nt == my_nt);
            const int  nsub = (!partial || (q0 & 32)) ? 2 : 1;
            bf16x8 pA, pB;
            subtile(0, nt*64, partial, pA, pB);
            pv(0, pA);
            pv(1, pB);
            if (nsub == 2) {
                subtile(1, nt*64 + 32, partial, pA, pB);
                pv(2, pA);
                pv(3, pB);
            }
        }
    }

    lsum += __shfl_xor(lsum, 32);
    const float inv = 1.0f / lsum;
    const int bb = bh >> 4, hh = bh & 15;
    float* orow = out + ((size_t)bb*T_ + q_abs)*KDIM + hh*64 + hi*4;
#pragma unroll
    for (int g = 0; g < 4; ++g) {
        f32x4 v0, v1;
#pragma unroll
        for (int j = 0; j < 4; ++j) { v0[j] = o0[g*4+j]*inv; v1[j] = o1[g*4+j]*inv; }
        *reinterpret_cast<f32x4*>(orow + g*8)      = v0;   // d = g*8 + hi*4 + j
        *reinterpret_cast<f32x4*>(orow + 32 + g*8) = v1;   // d-tile 1
    }
}

extern "C" void kernel_launch(void* const* d_in, const int* in_sizes, int n_in,
                              void* d_out, int out_size, void* d_ws, size_t ws_size,
                              hipStream_t stream) {
    (void)in_sizes; (void)n_in; (void)out_size; (void)ws_size;
    const float* x  = (const float*)d_in[0];
    const float* Wq = (const float*)d_in[1];
    const float* Wk = (const float*)d_in[2];
    const float* Wv = (const float*)d_in[3];
    float* out = (float*)d_out;

    bf16* xb  = (bf16*)d_ws;
    bf16* Wb  = xb + (size_t)M_*KDIM;
    bf16* Qb  = Wb + (size_t)3*KDIM*KDIM;
    bf16* Kb  = Qb + (size_t)M_*KDIM;
    bf16* Vtb = Kb + (size_t)M_*KDIM;

    const int n4x = M_*KDIM/4;
    const int n4w = KDIM*KDIM/4;
    cvt_f32_to_bf16<<<(n4x+255)/256, 256, 0, stream>>>(x,  xb, n4x);
    cvt_f32_to_bf16<<<(n4w+255)/256, 256, 0, stream>>>(Wq, Wb,               n4w);
    cvt_f32_to_bf16<<<(n4w+255)/256, 256, 0, stream>>>(Wk, Wb + (size_t)KDIM*KDIM,   n4w);
    cvt_f32_to_bf16<<<(n4w+255)/256, 256, 0, stream>>>(Wv, Wb + (size_t)2*KDIM*KDIM, n4w);

    proj_gemm<<<dim3(M_/128, KDIM/128, 3), 256, 0, stream>>>(xb, Wb, Qb, Kb, Vtb);
    flash_attn3<<<dim3(BH_*16), 256, 0, stream>>>(Qb, Kb, Vtb, out);
}